// Round 5
// baseline (1831.627 us; speedup 1.0000x reference)
//
#include <hip/hip_runtime.h>
#include <hip/hip_cooperative_groups.h>

namespace cg = cooperative_groups;

// Social-LSTM, single cooperative kernel. fp32 I/O.
// Block b owns pedestrians 4b..4b+3 for the whole T-loop: h,c persist in LDS.
// Per frame: grid.sync -> pool (stream grid row + gather U) -> gates -> lstm
// -> out-proj -> U' for next frame (all block-local except U).

#define TT    12
#define NN    1000
#define RNNW  128
#define OUTD  5
#define GROW  16000          // N*G floats per (t,n) grid row
#define NB    250
#define NTH   512

__device__ __forceinline__ float sigmf(float x) { return 1.f / (1.f + __expf(-x)); }

// U[n0+p][j] = sum_k sH[p][k] * W_socT[k][j],  j in {tid, tid+512}
__device__ __forceinline__ void compute_U(const float (*sH)[RNNW],
                                          const float* __restrict__ WsT2p,
                                          float* __restrict__ U, int n0, int tid) {
    const int jd = tid;
    float acc0[4] = {0.f, 0.f, 0.f, 0.f};
    float acc1[4] = {0.f, 0.f, 0.f, 0.f};
    for (int k = 0; k < RNNW; k += 4) {
        float4 a[4];
        #pragma unroll
        for (int p = 0; p < 4; ++p) a[p] = *(const float4*)(&sH[p][k]);
        const int r0 = (k >> 1), r1 = (k >> 1) + 1;
        float2 w00 = *(const float2*)(WsT2p + r0 * 2048 + jd * 2);
        float2 w01 = *(const float2*)(WsT2p + r0 * 2048 + (jd + 512) * 2);
        float2 w10 = *(const float2*)(WsT2p + r1 * 2048 + jd * 2);
        float2 w11 = *(const float2*)(WsT2p + r1 * 2048 + (jd + 512) * 2);
        #pragma unroll
        for (int p = 0; p < 4; ++p) {
            acc0[p] += a[p].x * w00.x + a[p].y * w00.y + a[p].z * w10.x + a[p].w * w10.y;
            acc1[p] += a[p].x * w01.x + a[p].y * w01.y + a[p].z * w11.x + a[p].w * w11.y;
        }
    }
    #pragma unroll
    for (int p = 0; p < 4; ++p) {
        U[(size_t)(n0 + p) * 1024 + jd]       = acc0[p];
        U[(size_t)(n0 + p) * 1024 + jd + 512] = acc1[p];
    }
}

__global__ __launch_bounds__(NTH) void k_main(
    const float* __restrict__ x_in, const unsigned int* __restrict__ grd,
    const float* __restrict__ h0, const float* __restrict__ c0,
    const float* __restrict__ W_in, const float* __restrict__ b_in,
    const float* __restrict__ W_soc, const float* __restrict__ b_soc,
    const float* __restrict__ W_ih, const float* __restrict__ W_hh,
    const float* __restrict__ b_ih, const float* __restrict__ b_hh,
    const float* __restrict__ W_out, const float* __restrict__ b_out,
    float* __restrict__ U, float* __restrict__ WsT2p, float* __restrict__ WcT2p,
    float* __restrict__ out)
{
    cg::grid_group grid = cg::this_grid();
    __shared__ float sH[4][RNNW], sC[4][RNNW], sA[4][RNNW];
    __shared__ float sG[4][512];
    __shared__ float sAcc[8][64];
    __shared__ float sRed[4][2][OUTD];

    const int tid  = threadIdx.x;
    const int lane = tid & 63;
    const int b    = blockIdx.x;
    const int n0   = b * 4;

    // ---- P0: weight repack (grid-stride) + persistent state load --------
    // WsT2p pair-packed k-major: [k/2][1024 j][2], j = g*64+e, from W_soc[e][g*128+k]
    for (int i = b * NTH + tid; i < 131072; i += NB * NTH) {
        int e = i >> 11, gk = i & 2047, g = gk >> 7, k = gk & 127;
        int j = g * 64 + e;
        WsT2p[(k >> 1) * 2048 + j * 2 + (k & 1)] = W_soc[i];
    }
    // WcT2p pair-packed: rows k<128 from W_ih, k>=128 from W_hh
    for (int i = b * NTH + tid; i < 65536; i += NB * NTH) {
        int j = i >> 7, k = i & 127;
        WcT2p[(k >> 1) * 1024 + j * 2 + (k & 1)]        = W_ih[i];
        WcT2p[((k >> 1) + 64) * 1024 + j * 2 + (k & 1)] = W_hh[i];
    }
    {
        int pl = tid >> 7, r = tid & 127;
        sH[pl][r] = h0[(n0 + pl) * RNNW + r];
        sC[pl][r] = c0[(n0 + pl) * RNNW + r];
    }
    __syncthreads();
    grid.sync();                       // weight packs ready everywhere
    compute_U(sH, WsT2p, U, n0, tid);  // U for frame 0

    for (int t = 0; t < TT; ++t) {
        grid.sync();                   // all U writes visible
        // ---- pool: wave wv handles half hf of ped pl's grid row ----------
        {
            const int wv = tid >> 6;
            const int pl = wv >> 1, hf = wv & 1;
            const unsigned int* gp = grd + (size_t)(t * NN + n0 + pl) * GROW;
            const int fbase = hf * 8000;
            float acc = 0.f;
            uint4 buf[4];
            #pragma unroll
            for (int q = 0; q < 4; ++q) {
                int f0 = fbase + q * 256 + lane * 4;
                buf[q] = make_uint4(0u, 0u, 0u, 0u);
                if (q * 256 + lane * 4 < 8000) buf[q] = *(const uint4*)(gp + f0);
            }
            for (int it = 0; it < 32; ++it) {
                uint4 cur = buf[it & 3];
                if (it + 4 < 32) {          // prefetch 4 windows ahead
                    int itn = it + 4;
                    int f0 = fbase + itn * 256 + lane * 4;
                    uint4 nv = make_uint4(0u, 0u, 0u, 0u);
                    if (itn * 256 + lane * 4 < 8000) nv = *(const uint4*)(gp + f0);
                    buf[it & 3] = nv;
                }
                const int base = fbase + it * 256;
                unsigned int va[4] = {cur.x, cur.y, cur.z, cur.w};
                #pragma unroll
                for (int sub = 0; sub < 4; ++sub) {
                    unsigned long long m = __ballot(va[sub] != 0u);
                    while (m) {
                        int bb = __builtin_ctzll(m); m &= m - 1;
                        int f = base + bb * 4 + sub;
                        acc += U[(size_t)(f >> 4) * 1024 + (f & 15) * 64 + lane];
                    }
                }
            }
            sAcc[wv][lane] = acc;
        }
        __syncthreads();
        // ---- combine: te + input embedding -> sA = [ie|te] ---------------
        if (tid < 256) {
            int pl = tid >> 6, e = tid & 63;
            float te = fmaxf(sAcc[2 * pl][e] + sAcc[2 * pl + 1][e] + b_soc[e], 0.f);
            float x0 = x_in[(size_t)(t * NN + n0 + pl) * 2 + 0];
            float x1 = x_in[(size_t)(t * NN + n0 + pl) * 2 + 1];
            float ie = fmaxf(W_in[e * 2 + 0] * x0 + W_in[e * 2 + 1] * x1 + b_in[e], 0.f);
            sA[pl][e]      = ie;
            sA[pl][64 + e] = te;
        }
        __syncthreads();
        // ---- gates: thread (jh, ph) -> gates {jh, jh+256} x peds {2ph,2ph+1}
        {
            const int jh = tid & 255, ph = tid >> 8;
            float g00 = 0.f, g01 = 0.f, g10 = 0.f, g11 = 0.f;
            #pragma unroll 4
            for (int k = 0; k < 128; k += 4) {          // [ie|te] part
                float4 aA = *(const float4*)(&sA[2 * ph][k]);
                float4 aB = *(const float4*)(&sA[2 * ph + 1][k]);
                const int r0 = (k >> 1), r1 = (k >> 1) + 1;
                float2 w00 = *(const float2*)(WcT2p + r0 * 1024 + jh * 2);
                float2 w01 = *(const float2*)(WcT2p + r0 * 1024 + (jh + 256) * 2);
                float2 w10 = *(const float2*)(WcT2p + r1 * 1024 + jh * 2);
                float2 w11 = *(const float2*)(WcT2p + r1 * 1024 + (jh + 256) * 2);
                g00 += aA.x * w00.x + aA.y * w00.y + aA.z * w10.x + aA.w * w10.y;
                g01 += aA.x * w01.x + aA.y * w01.y + aA.z * w11.x + aA.w * w11.y;
                g10 += aB.x * w00.x + aB.y * w00.y + aB.z * w10.x + aB.w * w10.y;
                g11 += aB.x * w01.x + aB.y * w01.y + aB.z * w11.x + aB.w * w11.y;
            }
            #pragma unroll 4
            for (int k = 0; k < 128; k += 4) {          // h part (rows 128+k)
                float4 aA = *(const float4*)(&sH[2 * ph][k]);
                float4 aB = *(const float4*)(&sH[2 * ph + 1][k]);
                const int r0 = 64 + (k >> 1), r1 = 64 + (k >> 1) + 1;
                float2 w00 = *(const float2*)(WcT2p + r0 * 1024 + jh * 2);
                float2 w01 = *(const float2*)(WcT2p + r0 * 1024 + (jh + 256) * 2);
                float2 w10 = *(const float2*)(WcT2p + r1 * 1024 + jh * 2);
                float2 w11 = *(const float2*)(WcT2p + r1 * 1024 + (jh + 256) * 2);
                g00 += aA.x * w00.x + aA.y * w00.y + aA.z * w10.x + aA.w * w10.y;
                g01 += aA.x * w01.x + aA.y * w01.y + aA.z * w11.x + aA.w * w11.y;
                g10 += aB.x * w00.x + aB.y * w00.y + aB.z * w10.x + aB.w * w10.y;
                g11 += aB.x * w01.x + aB.y * w01.y + aB.z * w11.x + aB.w * w11.y;
            }
            float bias0 = b_ih[jh] + b_hh[jh];
            float bias1 = b_ih[jh + 256] + b_hh[jh + 256];
            sG[2 * ph][jh]           = g00 + bias0;
            sG[2 * ph][jh + 256]     = g01 + bias1;
            sG[2 * ph + 1][jh]       = g10 + bias0;
            sG[2 * ph + 1][jh + 256] = g11 + bias1;
        }
        __syncthreads();
        // ---- LSTM elementwise (h,c stay in LDS) --------------------------
        {
            int pl = tid >> 7, r = tid & 127;
            float gi = sG[pl][r], gf = sG[pl][128 + r];
            float gg = sG[pl][256 + r], go = sG[pl][384 + r];
            float cn = sigmf(gf) * sC[pl][r] + sigmf(gi) * tanhf(gg);
            float hn = sigmf(go) * tanhf(cn);
            sC[pl][r] = cn;
            sH[pl][r] = hn;
        }
        __syncthreads();
        // ---- out projection: wave-parallel dot products ------------------
        {
            int pl = tid >> 7, p128 = tid & 127, wh = (tid >> 6) & 1;
            float v = sH[pl][p128];
            #pragma unroll
            for (int d = 0; d < OUTD; ++d) {
                float pr = v * W_out[d * RNNW + p128];
                #pragma unroll
                for (int off = 32; off > 0; off >>= 1) pr += __shfl_down(pr, off);
                if (lane == 0) sRed[pl][wh][d] = pr;
            }
        }
        __syncthreads();
        if (tid < 4 * OUTD) {
            int pl = tid / OUTD, d = tid % OUTD;
            out[((size_t)t * NN + n0 + pl) * OUTD + d] =
                sRed[pl][0][d] + sRed[pl][1][d] + b_out[d];
        }
        if (t < TT - 1) {
            __syncthreads();
            compute_U(sH, WsT2p, U, n0, tid);   // U for frame t+1
        }
    }
    // ---- final h,c ------------------------------------------------------
    {
        int pl = tid >> 7, r = tid & 127;
        out[(size_t)TT * NN * OUTD + (size_t)(n0 + pl) * RNNW + r] = sH[pl][r];
        out[(size_t)TT * NN * OUTD + (size_t)NN * RNNW + (size_t)(n0 + pl) * RNNW + r] = sC[pl][r];
    }
}

extern "C" void kernel_launch(void* const* d_in, const int* in_sizes, int n_in,
                              void* d_out, int out_size, void* d_ws, size_t ws_size,
                              hipStream_t stream) {
    const float* x_in       = (const float*)d_in[0];
    const unsigned int* grd = (const unsigned int*)d_in[1];
    const float* h0         = (const float*)d_in[2];
    const float* c0         = (const float*)d_in[3];
    const float* W_in       = (const float*)d_in[4];
    const float* b_in       = (const float*)d_in[5];
    const float* W_soc      = (const float*)d_in[6];
    const float* b_soc      = (const float*)d_in[7];
    const float* W_ih       = (const float*)d_in[8];
    const float* W_hh       = (const float*)d_in[9];
    const float* b_ih       = (const float*)d_in[10];
    const float* b_hh       = (const float*)d_in[11];
    const float* W_out      = (const float*)d_in[12];
    const float* b_out      = (const float*)d_in[13];
    float* out = (float*)d_out;

    float* U      = (float*)d_ws;              // 1000*1024
    float* WsT2p  = U + (size_t)NN * 1024;     // 131072
    float* WcT2p  = WsT2p + 131072;            // 131072

    void* args[] = {
        (void*)&x_in, (void*)&grd, (void*)&h0, (void*)&c0,
        (void*)&W_in, (void*)&b_in, (void*)&W_soc, (void*)&b_soc,
        (void*)&W_ih, (void*)&W_hh, (void*)&b_ih, (void*)&b_hh,
        (void*)&W_out, (void*)&b_out,
        (void*)&U, (void*)&WsT2p, (void*)&WcT2p, (void*)&out
    };
    hipLaunchCooperativeKernel((const void*)k_main, dim3(NB), dim3(NTH),
                               args, 0, stream);
}

// Round 6
// 711.997 us; speedup vs baseline: 2.5725x; 2.5725x over previous
//
#include <hip/hip_runtime.h>

// Social-LSTM on MI355X. fp32 I/O. Multi-kernel (graph-friendly), no coop.
// Per frame: k_pool (1000 blk: stream grid row + ballot-gather U -> A=[ie|te])
//            k_cell (250 blk x 512: gates + LSTM + out-proj + U' for t+1).
// U[p][g*64+e] = sum_k h[p][k]*W_soc[e][g*128+k]; te = relu(sum_nz U + b_soc).

#define TT    12
#define NN    1000
#define RNNW  128
#define OUTD  5
#define GROW  16000     // N*G floats per (t,n) grid row
#define UCW   1024

__device__ __forceinline__ float sigmf(float x) { return 1.f / (1.f + __expf(-x)); }

// ---- prep: pair-packed weight repacks + h/c init (round-5 verified math) --
// WsT2p[(k>>1)*2048 + (g*64+e)*2 + (k&1)] = W_soc[e][g*128+k]
// WcT2p[(k>>1)*1024 + j*2 + (k&1)] = W_ih[j][k];  rows 64.. from W_hh
__global__ void k_prep(const float* __restrict__ h0, const float* __restrict__ c0,
                       const float* __restrict__ W_soc,
                       const float* __restrict__ W_ih, const float* __restrict__ W_hh,
                       float* __restrict__ h, float* __restrict__ c,
                       float* __restrict__ WsT2p, float* __restrict__ WcT2p) {
    int i = blockIdx.x * 256 + threadIdx.x;
    if (i < 131072) {
        int e = i >> 11, gk = i & 2047, g = gk >> 7, k = gk & 127;
        int j = g * 64 + e;
        WsT2p[(k >> 1) * 2048 + j * 2 + (k & 1)] = W_soc[i];
    } else if (i < 196608) {
        int i2 = i - 131072;               // W_ih [512][128]
        int j = i2 >> 7, k = i2 & 127;
        WcT2p[(k >> 1) * 1024 + j * 2 + (k & 1)] = W_ih[i2];
    } else if (i < 262144) {
        int i3 = i - 196608;               // W_hh [512][128]
        int j = i3 >> 7, k = i3 & 127;
        WcT2p[((k >> 1) + 64) * 1024 + j * 2 + (k & 1)] = W_hh[i3];
    } else if (i < 262144 + NN * RNNW) {
        int i4 = i - 262144; h[i4] = h0[i4];
    } else if (i < 262144 + 2 * NN * RNNW) {
        int i5 = i - 262144 - NN * RNNW; c[i5] = c0[i5];
    }
}

// ---- U block-compute for 4 pedestrians, h in LDS (round-5 verified) ------
__device__ __forceinline__ void compute_U(const float (*sH)[RNNW],
                                          const float* __restrict__ WsT2p,
                                          float* __restrict__ U, int n0, int tid) {
    const int jd = tid;
    float acc0[4] = {0.f, 0.f, 0.f, 0.f};
    float acc1[4] = {0.f, 0.f, 0.f, 0.f};
    for (int k = 0; k < RNNW; k += 4) {
        float4 a[4];
        #pragma unroll
        for (int p = 0; p < 4; ++p) a[p] = *(const float4*)(&sH[p][k]);
        const int r0 = (k >> 1), r1 = (k >> 1) + 1;
        float2 w00 = *(const float2*)(WsT2p + r0 * 2048 + jd * 2);
        float2 w01 = *(const float2*)(WsT2p + r0 * 2048 + (jd + 512) * 2);
        float2 w10 = *(const float2*)(WsT2p + r1 * 2048 + jd * 2);
        float2 w11 = *(const float2*)(WsT2p + r1 * 2048 + (jd + 512) * 2);
        #pragma unroll
        for (int p = 0; p < 4; ++p) {
            acc0[p] += a[p].x * w00.x + a[p].y * w00.y + a[p].z * w10.x + a[p].w * w10.y;
            acc1[p] += a[p].x * w01.x + a[p].y * w01.y + a[p].z * w11.x + a[p].w * w11.y;
        }
    }
    #pragma unroll
    for (int p = 0; p < 4; ++p) {
        U[(size_t)(n0 + p) * UCW + jd]       = acc0[p];
        U[(size_t)(n0 + p) * UCW + jd + 512] = acc1[p];
    }
}

// ---- U for frame 0 from h (global) --------------------------------------
__global__ __launch_bounds__(512) void k_U0(const float* __restrict__ h,
                                            const float* __restrict__ WsT2p,
                                            float* __restrict__ U) {
    __shared__ float sH[4][RNNW];
    const int tid = threadIdx.x, n0 = blockIdx.x * 4;
    { int pl = tid >> 7, r = tid & 127; sH[pl][r] = h[(size_t)(n0 + pl) * RNNW + r]; }
    __syncthreads();
    compute_U(sH, WsT2p, U, n0, tid);
}

// ---- pooling + input embedding (round-3 verified): block per pedestrian --
__global__ __launch_bounds__(512) void k_pool(const unsigned int* __restrict__ grids,
                                              const float* __restrict__ x_in,
                                              const float* __restrict__ U,
                                              const float* __restrict__ W_in,
                                              const float* __restrict__ b_in,
                                              const float* __restrict__ b_soc,
                                              float* __restrict__ A, int t) {
    const int n = blockIdx.x;
    const int tid = threadIdx.x;
    const int lane = tid & 63, wave = tid >> 6;          // 8 waves
    const unsigned int* gp = grids + ((size_t)t * NN + n) * (size_t)GROW;
    float acc = 0.f;   // accumulator for e = lane
    for (int it = 0; it < 8; ++it) {
        int base = (it * 8 + wave) * 256;                // wave-uniform
        if (base >= GROW) break;
        int f0 = base + lane * 4;
        uint4 v = {0u, 0u, 0u, 0u};
        if (f0 < GROW) v = *(const uint4*)(gp + f0);     // GROW%4==0 -> safe
        unsigned int va[4] = {v.x, v.y, v.z, v.w};
        #pragma unroll
        for (int sub = 0; sub < 4; ++sub) {
            unsigned long long m = __ballot(va[sub] != 0u);
            while (m) {
                int b = __builtin_ctzll(m); m &= m - 1;
                int f = base + b * 4 + sub;
                acc += U[(size_t)(f >> 4) * UCW + (f & 15) * 64 + lane];
            }
        }
    }
    __shared__ float sAcc[8][64];
    sAcc[wave][lane] = acc;
    __syncthreads();
    if (tid < 64) {
        float s = 0.f;
        #pragma unroll
        for (int w = 0; w < 8; w++) s += sAcc[w][tid];
        float te = fmaxf(s + b_soc[tid], 0.f);
        float x0 = x_in[((size_t)t * NN + n) * 2 + 0];
        float x1 = x_in[((size_t)t * NN + n) * 2 + 1];
        float ie = fmaxf(W_in[tid * 2 + 0] * x0 + W_in[tid * 2 + 1] * x1 + b_in[tid], 0.f);
        A[(size_t)n * RNNW + tid]      = ie;
        A[(size_t)n * RNNW + 64 + tid] = te;
    }
}

// ---- cell: gates + LSTM + out-proj + U'(t+1). Block owns 4 pedestrians. --
__global__ __launch_bounds__(512) void k_cell(const float* __restrict__ A,
                                              float* __restrict__ h, float* __restrict__ c,
                                              const float* __restrict__ WcT2p,
                                              const float* __restrict__ WsT2p,
                                              const float* __restrict__ b_ih,
                                              const float* __restrict__ b_hh,
                                              const float* __restrict__ W_out,
                                              const float* __restrict__ b_out,
                                              float* __restrict__ U,
                                              float* __restrict__ out, int t, int doU) {
    __shared__ float sA[4][RNNW], sH[4][RNNW], sC[4][RNNW];
    __shared__ float sG[4][512];
    __shared__ float sRed[4][2][OUTD];
    const int tid = threadIdx.x;
    const int lane = tid & 63;
    const int n0 = blockIdx.x * 4;
    {   // load A, h, c for the 4 owned pedestrians
        int pl = tid >> 7, r = tid & 127;
        sA[pl][r] = A[(size_t)(n0 + pl) * RNNW + r];
        sH[pl][r] = h[(size_t)(n0 + pl) * RNNW + r];
        sC[pl][r] = c[(size_t)(n0 + pl) * RNNW + r];
    }
    __syncthreads();
    // ---- gates (round-5 verified): thread (jh, ph) -> gates {jh, jh+256}
    //      for peds {2ph, 2ph+1}
    {
        const int jh = tid & 255, ph = tid >> 8;
        float g00 = 0.f, g01 = 0.f, g10 = 0.f, g11 = 0.f;
        #pragma unroll 4
        for (int k = 0; k < 128; k += 4) {          // [ie|te] part
            float4 aA = *(const float4*)(&sA[2 * ph][k]);
            float4 aB = *(const float4*)(&sA[2 * ph + 1][k]);
            const int r0 = (k >> 1), r1 = (k >> 1) + 1;
            float2 w00 = *(const float2*)(WcT2p + r0 * 1024 + jh * 2);
            float2 w01 = *(const float2*)(WcT2p + r0 * 1024 + (jh + 256) * 2);
            float2 w10 = *(const float2*)(WcT2p + r1 * 1024 + jh * 2);
            float2 w11 = *(const float2*)(WcT2p + r1 * 1024 + (jh + 256) * 2);
            g00 += aA.x * w00.x + aA.y * w00.y + aA.z * w10.x + aA.w * w10.y;
            g01 += aA.x * w01.x + aA.y * w01.y + aA.z * w11.x + aA.w * w11.y;
            g10 += aB.x * w00.x + aB.y * w00.y + aB.z * w10.x + aB.w * w10.y;
            g11 += aB.x * w01.x + aB.y * w01.y + aB.z * w11.x + aB.w * w11.y;
        }
        #pragma unroll 4
        for (int k = 0; k < 128; k += 4) {          // h part (repack rows 64+)
            float4 aA = *(const float4*)(&sH[2 * ph][k]);
            float4 aB = *(const float4*)(&sH[2 * ph + 1][k]);
            const int r0 = 64 + (k >> 1), r1 = 64 + (k >> 1) + 1;
            float2 w00 = *(const float2*)(WcT2p + r0 * 1024 + jh * 2);
            float2 w01 = *(const float2*)(WcT2p + r0 * 1024 + (jh + 256) * 2);
            float2 w10 = *(const float2*)(WcT2p + r1 * 1024 + jh * 2);
            float2 w11 = *(const float2*)(WcT2p + r1 * 1024 + (jh + 256) * 2);
            g00 += aA.x * w00.x + aA.y * w00.y + aA.z * w10.x + aA.w * w10.y;
            g01 += aA.x * w01.x + aA.y * w01.y + aA.z * w11.x + aA.w * w11.y;
            g10 += aB.x * w00.x + aB.y * w00.y + aB.z * w10.x + aB.w * w10.y;
            g11 += aB.x * w01.x + aB.y * w01.y + aB.z * w11.x + aB.w * w11.y;
        }
        float bias0 = b_ih[jh] + b_hh[jh];
        float bias1 = b_ih[jh + 256] + b_hh[jh + 256];
        sG[2 * ph][jh]           = g00 + bias0;
        sG[2 * ph][jh + 256]     = g01 + bias1;
        sG[2 * ph + 1][jh]       = g10 + bias0;
        sG[2 * ph + 1][jh + 256] = g11 + bias1;
    }
    __syncthreads();
    // ---- LSTM elementwise ----
    {
        int pl = tid >> 7, r = tid & 127;
        float gi = sG[pl][r], gf = sG[pl][128 + r];
        float gg = sG[pl][256 + r], go = sG[pl][384 + r];
        float cn = sigmf(gf) * sC[pl][r] + sigmf(gi) * tanhf(gg);
        float hn = sigmf(go) * tanhf(cn);
        sC[pl][r] = cn;
        sH[pl][r] = hn;
        c[(size_t)(n0 + pl) * RNNW + r] = cn;
        h[(size_t)(n0 + pl) * RNNW + r] = hn;
    }
    __syncthreads();
    // ---- out projection (round-5 verified shuffle reduce) ----
    {
        int pl = tid >> 7, p128 = tid & 127, wh = (tid >> 6) & 1;
        float v = sH[pl][p128];
        #pragma unroll
        for (int d = 0; d < OUTD; ++d) {
            float pr = v * W_out[d * RNNW + p128];
            #pragma unroll
            for (int off = 32; off > 0; off >>= 1) pr += __shfl_down(pr, off);
            if (lane == 0) sRed[pl][wh][d] = pr;
        }
    }
    __syncthreads();
    if (tid < 4 * OUTD) {
        int pl = tid / OUTD, d = tid % OUTD;
        out[((size_t)t * NN + n0 + pl) * OUTD + d] =
            sRed[pl][0][d] + sRed[pl][1][d] + b_out[d];
    }
    // ---- U for frame t+1 ----
    if (doU) compute_U(sH, WsT2p, U, n0, tid);
}

// ---- final: h,c -> tail of d_out ----------------------------------------
__global__ void k_final(const float* __restrict__ h, const float* __restrict__ c,
                        float* __restrict__ out) {
    int i = blockIdx.x * 256 + threadIdx.x;
    if (i < NN * RNNW) {
        out[TT * NN * OUTD + i] = h[i];
        out[TT * NN * OUTD + NN * RNNW + i] = c[i];
    }
}

extern "C" void kernel_launch(void* const* d_in, const int* in_sizes, int n_in,
                              void* d_out, int out_size, void* d_ws, size_t ws_size,
                              hipStream_t stream) {
    const float* x_in       = (const float*)d_in[0];
    const unsigned int* grd = (const unsigned int*)d_in[1];
    const float* h0         = (const float*)d_in[2];
    const float* c0         = (const float*)d_in[3];
    const float* W_in       = (const float*)d_in[4];
    const float* b_in       = (const float*)d_in[5];
    const float* W_soc      = (const float*)d_in[6];
    const float* b_soc      = (const float*)d_in[7];
    const float* W_ih       = (const float*)d_in[8];
    const float* W_hh       = (const float*)d_in[9];
    const float* b_ih       = (const float*)d_in[10];
    const float* b_hh       = (const float*)d_in[11];
    const float* W_out      = (const float*)d_in[12];
    const float* b_out      = (const float*)d_in[13];
    float* out = (float*)d_out;

    float* h      = (float*)d_ws;                 // 128000
    float* c      = h + NN * RNNW;                // 128000
    float* U      = c + NN * RNNW;                // 1,024,000
    float* A      = U + (size_t)NN * UCW;         // 128,000
    float* WsT2p  = A + (size_t)NN * RNNW;        // 131,072
    float* WcT2p  = WsT2p + 131072;               // 131,072   (~6.1 MB)

    hipLaunchKernelGGL(k_prep, dim3(2024), dim3(256), 0, stream,
                       h0, c0, W_soc, W_ih, W_hh, h, c, WsT2p, WcT2p);
    hipLaunchKernelGGL(k_U0, dim3(250), dim3(512), 0, stream, h, WsT2p, U);
    for (int t = 0; t < TT; ++t) {
        hipLaunchKernelGGL(k_pool, dim3(NN), dim3(512), 0, stream,
                           grd, x_in, U, W_in, b_in, b_soc, A, t);
        hipLaunchKernelGGL(k_cell, dim3(250), dim3(512), 0, stream,
                           A, h, c, WcT2p, WsT2p, b_ih, b_hh, W_out, b_out,
                           U, out, t, (t < TT - 1) ? 1 : 0);
    }
    hipLaunchKernelGGL(k_final, dim3(500), dim3(256), 0, stream, h, c, out);
}